// Round 4
// baseline (14805.527 us; speedup 1.0000x reference)
//
#include <hip/hip_runtime.h>
#include <math.h>

#define DIM   768
#define NHEAD 16
#define DHEAD 48
#define NLAY  3
#define NTOK  256
#define BATCH 4
#define NPAST_ 16
#define NFUT  20
#define CCTX  273              // NTOK + 1 + NPAST
#define SMAXT 293              // CCTX + NFUT
#define MROWS 1172             // BATCH * SMAXT
#define NEGV  (-1.0e9f)
#define QKVPLANE 900096        // BATCH*NHEAD*SMAXT*48

typedef unsigned short u16;
typedef unsigned int   u32;
typedef __attribute__((ext_vector_type(8))) short short8;
typedef __attribute__((ext_vector_type(4))) float floatx4;

__device__ inline u16 f2bf(float x) {
    union { float f; u32 u; } v; v.f = x;
    u32 r = v.u + 0x7fffu + ((v.u >> 16) & 1u);
    return (u16)(r >> 16);
}

__device__ inline float gelu_f(float x) {
    return 0.5f * x * (1.0f + erff(x * 0.70710678118654752f));
}

__device__ inline void gll16(const u16* g, u16* l) {
    __builtin_amdgcn_global_load_lds((const __attribute__((address_space(1))) void*)g,
                                     (__attribute__((address_space(3))) void*)l, 16, 0, 0);
}

// ---------------------------------------------------------------- init X_base
__global__ void init_base(const float* __restrict__ img, const float* __restrict__ past,
                          const int* __restrict__ intent, const float* __restrict__ pos,
                          const float* __restrict__ futq, const float* __restrict__ iemb,
                          const float* __restrict__ temb, const float* __restrict__ Wp,
                          const float* __restrict__ bp, const float* __restrict__ Wpp,
                          const float* __restrict__ bpp, float* __restrict__ X)
{
    int r = blockIdx.x;
    int b = r / SMAXT, s = r % SMAXT;
    for (int j = threadIdx.x; j < DIM; j += blockDim.x) {
        float v;
        if (s < NTOK) {
            v = img[(long)(b * NTOK + s) * DIM + j] + pos[(long)s * DIM + j];
        } else if (s == NTOK) {
            int idx = intent[b] - 1; idx = idx < 0 ? 0 : (idx > 2 ? 2 : idx);
            v = iemb[(long)idx * DIM + j];
        } else if (s < CCTX) {
            int i = s - (NTOK + 1);
            v = bp[j] + bpp[j] + temb[(long)i * DIM + j];
            const float* pr = past + (long)(b * NPAST_ + i) * 6;
            #pragma unroll
            for (int c = 0; c < 6; ++c) v += pr[c] * Wp[(long)c * DIM + j];
            v += pr[0] * Wpp[j] + pr[1] * Wpp[DIM + j];
        } else {
            int f = s - CCTX;
            v = futq[(long)f * DIM + j] + temb[(long)(NPAST_ + f) * DIM + j];
        }
        X[(long)r * DIM + j] = v;
    }
}

// ---------------------------------------------------------------- weight convert + transpose: W[K,N] fp32 -> Wt[N,K] bf16
__global__ void convert_transpose(const float* __restrict__ W, u16* __restrict__ Wt, int K, int N)
{
    __shared__ float tile[32][33];
    long lstride = (long)K * N;
    W  += blockIdx.z * lstride;
    Wt += blockIdx.z * lstride;
    int n0 = blockIdx.x * 32, k0 = blockIdx.y * 32;
    int tx = threadIdx.x & 31, ty = threadIdx.x >> 5;
    for (int i = ty; i < 32; i += 8)
        tile[i][tx] = W[(long)(k0 + i) * N + n0 + tx];
    __syncthreads();
    for (int i = ty; i < 32; i += 8)
        Wt[(long)(n0 + i) * K + k0 + tx] = f2bf(tile[tx][i]);
}

// ---------------------------------------------------------------- bf16 MFMA GEMM
// Wave tile 32x32; block = (WM*32) x (WN*32). BK=64, double-buffered, gll for B.
// MODE 0: A bf16 (gll); out fp32 = acc + bias + res.
// MODE 1: A fp32, fused LN (self-computed stats prologue); relu -> bf16 out.
// MODE 2: A fp32, fused LN; out fp32 qkv-permuted [which][b*16+h][s][48], q pre-scaled.
template<int WM, int WN, int MODE>
__launch_bounds__(WM*WN*64)
__global__ void gemm_mfma(const void* __restrict__ Av, const u16* __restrict__ Wt,
                          const float* __restrict__ bias, const float* __restrict__ res,
                          const float* __restrict__ gg, const float* __restrict__ bb,
                          void* __restrict__ outv, int M, int N, int K)
{
    constexpr int NWAVE = WM * WN;
    constexpr int T = NWAVE * 64;
    constexpr int BM = WM * 32, BN = WN * 32;
    constexpr int NSA = BM / 16, NSB = BN / 16;
    constexpr int UA = (BM * 64) / (T * 8);
    constexpr int UB = (BN * 64) / (T * 8);
    constexpr bool LN = (MODE == 1 || MODE == 2);

    __shared__ __align__(16) u16 As[2][BM * 64];
    __shared__ __align__(16) u16 Bs[2][BN * 64];
    __shared__ float sExtra[LN ? (1536 + 2 * BM) : 4];

    const int tid = threadIdx.x, lane = tid & 63, w = tid >> 6;
    const int wm = w % WM, wn = w / WM;
    const int lm = lane & 15, lk = lane >> 4;
    const int m0 = blockIdx.y * BM, n0 = blockIdx.x * BN;
    const int KT = K >> 6;

    int grA[UA], kkA[UA], lrA[UA];
    #pragma unroll
    for (int q = 0; q < UA; ++q) {
        int c = q * NWAVE + w;
        int t = c / NSA, sub = c % NSA;
        int lr = sub * 16 + lm;
        lrA[q] = lr;
        int gr = m0 + lr; if (gr >= M) gr = M - 1;
        grA[q] = gr;
        kkA[q] = t * 32 + lk * 8;
    }

    floatx4 acc[2][2];
    #pragma unroll
    for (int i = 0; i < 2; ++i)
        #pragma unroll
        for (int j = 0; j < 2; ++j) acc[i][j] = (floatx4){0.f, 0.f, 0.f, 0.f};

    float4 rx[UA][2];
    float mA[UA], rA[UA];

    auto stage_b = [&](int k0, int buf) {
        #pragma unroll
        for (int q = 0; q < UB; ++q) {
            int c = q * NWAVE + w;
            int t = c / NSB, sub = c % NSB;
            const u16* gp = Wt + (long)(n0 + sub * 16 + lm) * K + k0 + t * 32 + lk * 8;
            gll16(gp, &Bs[buf][c * 512]);
        }
    };
    auto stage_a = [&](int k0, int buf) {
        #pragma unroll
        for (int q = 0; q < UA; ++q) {
            if (MODE == 0) {
                int c = q * NWAVE + w;
                gll16((const u16*)Av + (long)grA[q] * K + k0 + kkA[q], &As[buf][c * 512]);
            } else {
                const float* X = (const float*)Av;
                rx[q][0] = *(const float4*)(X + (long)grA[q] * K + k0 + kkA[q]);
                rx[q][1] = *(const float4*)(X + (long)grA[q] * K + k0 + kkA[q] + 4);
            }
        }
    };
    auto write_a = [&](int k0, int buf) {   // LN modes only: LN math deferred to here
        #pragma unroll
        for (int q = 0; q < UA; ++q) {
            int c = q * NWAVE + w;
            short8 r;
            #pragma unroll
            for (int h = 0; h < 2; ++h) {
                float4 x = rx[q][h];
                int kc = k0 + kkA[q] + h * 4;
                const float* gp = &sExtra[kc];
                const float* bp = &sExtra[768 + kc];
                r[h*4+0] = (short)f2bf((x.x - mA[q]) * rA[q] * gp[0] + bp[0]);
                r[h*4+1] = (short)f2bf((x.y - mA[q]) * rA[q] * gp[1] + bp[1]);
                r[h*4+2] = (short)f2bf((x.z - mA[q]) * rA[q] * gp[2] + bp[2]);
                r[h*4+3] = (short)f2bf((x.w - mA[q]) * rA[q] * gp[3] + bp[3]);
            }
            *(short8*)&As[buf][(c * 64 + lane) * 8] = r;
        }
    };

    // ---- prologue: first-tile loads in flight, then stats (LN), then commit
    stage_b(0, 0);
    stage_a(0, 0);
    if (LN) {
        for (int i = tid; i < 768; i += T) { sExtra[i] = gg[i]; sExtra[768 + i] = bb[i]; }
        float* sMean = &sExtra[1536];
        float* sRstd = &sExtra[1536 + BM];
        constexpr int RPW = BM / NWAVE;
        for (int r = 0; r < RPW; ++r) {
            int row = w * RPW + r;
            int gr = m0 + row; if (gr >= M) gr = M - 1;
            const float* xr = (const float*)Av + (long)gr * 768;
            float s = 0.f, qq = 0.f;
            #pragma unroll
            for (int c4 = 0; c4 < 3; ++c4) {
                float4 v = *(const float4*)(xr + c4 * 256 + lane * 4);
                s += v.x + v.y + v.z + v.w;
                qq += v.x * v.x + v.y * v.y + v.z * v.z + v.w * v.w;
            }
            #pragma unroll
            for (int o = 32; o; o >>= 1) { s += __shfl_down(s, o, 64); qq += __shfl_down(qq, o, 64); }
            if (lane == 0) {
                float mm = s * (1.f / 768.f);
                float var = qq * (1.f / 768.f) - mm * mm;
                sMean[row] = mm;
                sRstd[row] = rsqrtf(var + 1e-5f);
            }
        }
        __syncthreads();
        #pragma unroll
        for (int q = 0; q < UA; ++q) { mA[q] = sMean[lrA[q]]; rA[q] = sRstd[lrA[q]]; }
        write_a(0, 0);
    }
    __syncthreads();

    for (int k = 0; k < KT; ++k) {
        int cur = k & 1, nxt = cur ^ 1;
        bool more = (k + 1 < KT);
        if (more) { stage_b((k + 1) << 6, nxt); stage_a((k + 1) << 6, nxt); }
        #pragma unroll
        for (int t = 0; t < 2; ++t) {
            short8 af[2], bfr[2];
            #pragma unroll
            for (int i = 0; i < 2; ++i)
                af[i] = *(const short8*)&As[cur][((t * NSA + wm * 2 + i) * 64 + lk * 16 + lm) * 8];
            #pragma unroll
            for (int j = 0; j < 2; ++j)
                bfr[j] = *(const short8*)&Bs[cur][((t * NSB + wn * 2 + j) * 64 + lk * 16 + lm) * 8];
            #pragma unroll
            for (int i = 0; i < 2; ++i)
                #pragma unroll
                for (int j = 0; j < 2; ++j)
                    acc[i][j] = __builtin_amdgcn_mfma_f32_16x16x32_bf16(af[i], bfr[j], acc[i][j], 0, 0, 0);
        }
        if (LN && more) write_a((k + 1) << 6, nxt);
        __syncthreads();
    }

    // ---- epilogue
    #pragma unroll
    for (int j = 0; j < 2; ++j) {
        int col = n0 + wn * 32 + j * 16 + lm;
        float bv = bias[col];
        #pragma unroll
        for (int i = 0; i < 2; ++i) {
            #pragma unroll
            for (int rr = 0; rr < 4; ++rr) {
                int row = m0 + wm * 32 + i * 16 + lk * 4 + rr;
                if (row >= M) continue;
                float val = acc[i][j][rr] + bv;
                if (MODE == 0) {
                    val += res[(long)row * N + col];
                    ((float*)outv)[(long)row * N + col] = val;
                } else if (MODE == 1) {
                    ((u16*)outv)[(long)row * N + col] = f2bf(fmaxf(val, 0.f));
                } else {
                    int which = col >= 1536 ? 2 : (col >= 768 ? 1 : 0);
                    int rem = col - which * 768;
                    int h = rem / 48, d = rem - h * 48;
                    if (which == 0) val *= 0.14433756729740643f;
                    int b2 = row / SMAXT, s = row - b2 * SMAXT;
                    ((float*)outv)[(long)which * QKVPLANE + ((long)(b2 * 16 + h) * SMAXT + s) * 48 + d] = val;
                }
            }
        }
    }
}

// ---------------------------------------------------------------- attention (fp32, head-major qkv, q pre-scaled)
__launch_bounds__(256)
__global__ void attn_kernel(const float* __restrict__ qkv, u16* __restrict__ o, int S)
{
    int bh = blockIdx.y;
    int b = bh >> 4, h = bh & 15;
    int q0 = blockIdx.x * 16;
    if (q0 >= S) return;
    __shared__ float qs[16][48];
    __shared__ float kbuf[3328];
    __shared__ float sc[16][304];
    int t = threadIdx.x;
    const float* qp = qkv + (long)bh * SMAXT * 48;
    const float* kp = qp + QKVPLANE;
    const float* vp = qp + 2 * QKVPLANE;

    for (int lin = t; lin < 16 * 48; lin += 256) {
        int i2 = lin / 48, d = lin % 48;
        int qi2 = q0 + i2; if (qi2 > S - 1) qi2 = S - 1;
        qs[i2][d] = qp[(long)qi2 * 48 + d];
    }
    __syncthreads();
    int i = t >> 4, j = t & 15;
    int qi = q0 + i;
    float4 q4[12];
    #pragma unroll
    for (int k4 = 0; k4 < 12; ++k4) q4[k4] = *(const float4*)&qs[i][k4 * 4];

    for (int s0 = 0; s0 < S; s0 += 64) {
        int ns = S - s0; if (ns > 64) ns = 64;
        __syncthreads();
        for (int lin = t; lin < 64 * 12; lin += 256) {
            int ss = lin / 12, d4 = lin % 12;
            float4 kv = make_float4(0.f, 0.f, 0.f, 0.f);
            if (ss < ns) kv = *(const float4*)(kp + (long)(s0 + ss) * 48 + d4 * 4);
            *(float4*)&kbuf[ss * 52 + d4 * 4] = kv;
        }
        __syncthreads();
        #pragma unroll
        for (int u = 0; u < 4; ++u) {
            int ss = j + 16 * u;
            float acc = 0.f;
            #pragma unroll
            for (int k4 = 0; k4 < 12; ++k4) {
                float4 kk = *(const float4*)&kbuf[ss * 52 + k4 * 4];
                acc += q4[k4].x * kk.x + q4[k4].y * kk.y + q4[k4].z * kk.z + q4[k4].w * kk.w;
            }
            int s = s0 + ss;
            if (ss < ns) {
                bool masked = (qi >= CCTX) && (s > qi);
                sc[i][s] = masked ? acc + NEGV : acc;
            }
        }
    }
    __syncthreads();

    float mx = -1e30f;
    for (int s = j; s < S; s += 16) mx = fmaxf(mx, sc[i][s]);
    #pragma unroll
    for (int m = 8; m; m >>= 1) mx = fmaxf(mx, __shfl_xor(mx, m, 16));
    int Sp = (S + 3) & ~3;
    float sum = 0.f;
    for (int s = j; s < Sp; s += 16) {
        float e = (s < S) ? __expf(sc[i][s] - mx) : 0.f;
        sc[i][s] = e; sum += e;
    }
    #pragma unroll
    for (int m = 8; m; m >>= 1) sum += __shfl_xor(sum, m, 16);
    float inv = 1.f / sum;

    float oc0 = 0.f, oc1 = 0.f, oc2 = 0.f;
    int d0 = j * 3;
    for (int s0 = 0; s0 < S; s0 += 64) {
        int ns4 = Sp - s0; if (ns4 > 64) ns4 = 64;
        __syncthreads();
        for (int lin = t; lin < 64 * 48; lin += 256) {
            int ss = lin / 48, d = lin % 48;
            float v = 0.f;
            int s = s0 + ss;
            if (s < S) v = vp[(long)s * 48 + d];
            kbuf[d * 68 + ss] = v;
        }
        __syncthreads();
        for (int sb = 0; sb < ns4; sb += 4) {
            float4 a4 = *(const float4*)&sc[i][s0 + sb];
            float4 v0 = *(const float4*)&kbuf[d0 * 68 + sb];
            float4 v1 = *(const float4*)&kbuf[(d0 + 1) * 68 + sb];
            float4 v2 = *(const float4*)&kbuf[(d0 + 2) * 68 + sb];
            oc0 += a4.x * v0.x + a4.y * v0.y + a4.z * v0.z + a4.w * v0.w;
            oc1 += a4.x * v1.x + a4.y * v1.y + a4.z * v1.z + a4.w * v1.w;
            oc2 += a4.x * v2.x + a4.y * v2.y + a4.z * v2.z + a4.w * v2.w;
        }
    }
    if (qi < S) {
        u16* orow = o + ((long)(b * SMAXT + qi)) * 768 + h * 48 + d0;
        orow[0] = f2bf(oc0 * inv); orow[1] = f2bf(oc1 * inv); orow[2] = f2bf(oc2 * inv);
    }
}

// ---------------------------------------------------------------- decoder gelu GEMM (4x768 @ 768x768), fp32
__launch_bounds__(256)
__global__ void dec_gelu(const float* __restrict__ src, long srowstride,
                         const float* __restrict__ W, const float* __restrict__ bias,
                         float* __restrict__ dst)
{
    int b = blockIdx.y;
    int jb = blockIdx.x;
    __shared__ float s0buf[768];
    __shared__ float red[4][64];
    int tid = threadIdx.x;
    const float* sr = src + (long)b * srowstride;
    for (int i = tid; i < 768; i += 256) s0buf[i] = sr[i];
    __syncthreads();
    int jj = tid & 63, ig = tid >> 6;
    int jcol = jb * 64 + jj;
    float acc = 0.f;
    const float* wp = W + (long)(ig * 192) * 768 + jcol;
    #pragma unroll 4
    for (int i = 0; i < 192; ++i) acc += s0buf[ig * 192 + i] * wp[(long)i * 768];
    red[ig][jj] = acc;
    __syncthreads();
    if (ig == 0) {
        float a = red[0][jj] + red[1][jj] + red[2][jj] + red[3][jj] + bias[jcol];
        dst[(long)b * 768 + jcol] = gelu_f(a);
    }
}

// ---------------------------------------------------------------- decoder final
__launch_bounds__(256)
__global__ void dec_final(const float* __restrict__ d2, const float* __restrict__ Wd3,
                          const float* __restrict__ bd3, const float* __restrict__ Wpp,
                          const float* __restrict__ bpp, const float* __restrict__ gpp,
                          const float* __restrict__ bepp, float* __restrict__ out,
                          float* __restrict__ X, int t)
{
    int b = blockIdx.x;
    int tid = threadIdx.x;
    __shared__ float red[2][4];
    __shared__ float pp[2];
    const float* dr = d2 + (long)b * 768;
    float a0 = 0.f, a1 = 0.f;
    for (int i = tid; i < 768; i += 256) {
        float v = dr[i];
        a0 += v * Wd3[2 * i]; a1 += v * Wd3[2 * i + 1];
    }
    for (int off = 32; off; off >>= 1) { a0 += __shfl_down(a0, off, 64); a1 += __shfl_down(a1, off, 64); }
    int wid = tid >> 6, lane = tid & 63;
    if (!lane) { red[0][wid] = a0; red[1][wid] = a1; }
    __syncthreads();
    if (!tid) {
        float p0 = red[0][0] + red[0][1] + red[0][2] + red[0][3] + bd3[0];
        float p1 = red[1][0] + red[1][1] + red[1][2] + red[1][3] + bd3[1];
        out[(long)(b * NFUT + t) * 2 + 0] = p0;
        out[(long)(b * NFUT + t) * 2 + 1] = p1;
        pp[0] = p0; pp[1] = p1;
    }
    __syncthreads();
    if (t == NFUT - 1) return;
    float p0 = pp[0], p1 = pp[1];
    float pv[3]; float s = 0.f;
    #pragma unroll
    for (int u = 0; u < 3; ++u) {
        int jcol = tid + 256 * u;
        pv[u] = p0 * Wpp[jcol] + p1 * Wpp[768 + jcol] + bpp[jcol];
        s += pv[u];
    }
    for (int off = 32; off; off >>= 1) s += __shfl_down(s, off, 64);
    __syncthreads();
    if (!lane) red[0][wid] = s;
    __syncthreads();
    float mean = (red[0][0] + red[0][1] + red[0][2] + red[0][3]) * (1.f / 768.f);
    float vs = 0.f;
    #pragma unroll
    for (int u = 0; u < 3; ++u) { float d = pv[u] - mean; vs += d * d; }
    for (int off = 32; off; off >>= 1) vs += __shfl_down(vs, off, 64);
    __syncthreads();
    if (!lane) red[1][wid] = vs;
    __syncthreads();
    float var = (red[1][0] + red[1][1] + red[1][2] + red[1][3]) * (1.f / 768.f);
    float inv = rsqrtf(var + 1e-5f);
    float* Xr = X + ((long)(b * SMAXT + CCTX + t + 1)) * 768;
    #pragma unroll
    for (int u = 0; u < 3; ++u) {
        int jcol = tid + 256 * u;
        float y = (pv[u] - mean) * inv * gpp[jcol] + bepp[jcol];
        if (y > 0.f) Xr[jcol] += y;
    }
}

// ---------------------------------------------------------------- launch
extern "C" void kernel_launch(void* const* d_in, const int* in_sizes, int n_in,
                              void* d_out, int out_size, void* d_ws, size_t ws_size,
                              hipStream_t stream)
{
    const float* img    = (const float*)d_in[0];
    const float* past   = (const float*)d_in[1];
    const int*   intent = (const int*)d_in[2];
    const float* pos    = (const float*)d_in[3];
    const float* futq   = (const float*)d_in[4];
    const float* iemb   = (const float*)d_in[5];
    const float* temb   = (const float*)d_in[6];
    const float* W_past = (const float*)d_in[7];
    const float* b_past = (const float*)d_in[8];
    const float* W_ppos = (const float*)d_in[9];
    const float* b_ppos = (const float*)d_in[10];
    const float* W_pp   = (const float*)d_in[11];
    const float* b_pp   = (const float*)d_in[12];
    const float* g_pp   = (const float*)d_in[13];
    const float* be_pp  = (const float*)d_in[14];
    const float* Wqkv   = (const float*)d_in[15];
    const float* bqkv   = (const float*)d_in[16];
    const float* Wo     = (const float*)d_in[17];
    const float* bo     = (const float*)d_in[18];
    const float* g1     = (const float*)d_in[19];
    const float* beta1  = (const float*)d_in[20];
    const float* g2     = (const float*)d_in[21];
    const float* beta2  = (const float*)d_in[22];
    const float* W1     = (const float*)d_in[23];
    const float* bf1    = (const float*)d_in[24];
    const float* W2     = (const float*)d_in[25];
    const float* bf2    = (const float*)d_in[26];
    const float* Wd1    = (const float*)d_in[27];
    const float* bd1    = (const float*)d_in[28];
    const float* Wd2    = (const float*)d_in[29];
    const float* bd2    = (const float*)d_in[30];
    const float* Wd3    = (const float*)d_in[31];
    const float* bd3    = (const float*)d_in[32];
    float* out = (float*)d_out;

    float* ws     = (float*)d_ws;
    float* Xb     = ws;                      // 900096 f
    float* xbuf   = ws + 900096;             // 900096 f
    float* qkvbuf = ws + 1800192;            // 2700288 f
    u16*   aobuf  = (u16*)(ws + 4500480);    // 900096 bf16
    u16*   big    = (u16*)(ws + 4950528);    // 1172*3072 bf16
    float* d1ws   = ws + 6750720;            // 3072 f
    float* d2ws   = ws + 6753792;            // 3072 f
    u16*   WqkvT  = (u16*)(ws + 6756864);    // 3*2304*768 bf16
    u16*   WoT    = (u16*)(ws + 9411072);    // 3*768*768
    u16*   W1T    = (u16*)(ws + 10295808);   // 3*768*3072
    u16*   W2T    = (u16*)(ws + 13834752);   // 3*3072*768

    convert_transpose<<<dim3(2304/32, 768/32, 3), 256, 0, stream>>>(Wqkv, WqkvT, 768, 2304);
    convert_transpose<<<dim3(768/32, 768/32, 3), 256, 0, stream>>>(Wo, WoT, 768, 768);
    convert_transpose<<<dim3(3072/32, 768/32, 3), 256, 0, stream>>>(W1, W1T, 768, 3072);
    convert_transpose<<<dim3(768/32, 3072/32, 3), 256, 0, stream>>>(W2, W2T, 3072, 768);

    init_base<<<dim3(MROWS), dim3(256), 0, stream>>>(img, past, intent, pos, futq, iemb,
                                                     temb, W_past, b_past, W_ppos, b_ppos, Xb);

    for (int t = 0; t < NFUT; ++t) {
        int S = CCTX + t + 1;
        const float* src = Xb;
        for (int l = 0; l < NLAY; ++l) {
            // QKV (fused LN1), 64x64 tiles, 684 blocks
            gemm_mfma<2, 2, 2><<<dim3(36, 19), 256, 0, stream>>>(
                src, WqkvT + (long)l * 768 * 2304, bqkv + l * 2304, nullptr,
                g1 + l * 768, beta1 + l * 768, qkvbuf, MROWS, 2304, 768);
            attn_kernel<<<dim3((S + 15) / 16, 64), dim3(256), 0, stream>>>(qkvbuf, aobuf, S);
            // Wo + residual, 32x64 tiles, 444 blocks
            gemm_mfma<1, 2, 0><<<dim3(12, 37), 128, 0, stream>>>(
                aobuf, WoT + (long)l * 768 * 768, bo + l * 768, src,
                nullptr, nullptr, xbuf, MROWS, 768, 768);
            // FFN1 (fused LN2), relu->bf16, 912 blocks
            gemm_mfma<2, 2, 1><<<dim3(48, 19), 256, 0, stream>>>(
                xbuf, W1T + (long)l * 768 * 3072, bf1 + l * 3072, nullptr,
                g2 + l * 768, beta2 + l * 768, big, MROWS, 3072, 768);
            // FFN2 + residual, 32x64 tiles, 444 blocks
            gemm_mfma<1, 2, 0><<<dim3(12, 37), 128, 0, stream>>>(
                big, W2T + (long)l * 3072 * 768, bf2 + l * 768, xbuf,
                nullptr, nullptr, xbuf, MROWS, 768, 3072);
            src = xbuf;
        }
        dec_gelu<<<dim3(12, 4), dim3(256), 0, stream>>>(xbuf + (long)(S - 1) * 768, (long)SMAXT * 768, Wd1, bd1, d1ws);
        dec_gelu<<<dim3(12, 4), dim3(256), 0, stream>>>(d1ws, 768L, Wd2, bd2, d2ws);
        dec_final<<<dim3(4), dim3(256), 0, stream>>>(d2ws, Wd3, bd3, W_pp, b_pp, g_pp, be_pp, out, Xb, t);
    }
}